// Round 11
// baseline (233.238 us; speedup 1.0000x reference)
//
#include <hip/hip_runtime.h>
#include <stdint.h>

// R11: binary conv on the MATRIX pipe. pack_kernel = R4's verified bitpack
// (+ extra block builds i8 B-fragments and the boundary-correction table).
// conv_kernel: one wave = (n, h, og-pair); 18 resident B-frags; per 16-px
// M-tile: 9 taps x {u32 bit-word load -> 16-bit->16-i8 expand -> 2 MFMA
// mfma_i32_16x16x64_i8}; epilogue adds boundary correction, 2 f32x4 stores.
// NO LDS, NO barriers in conv -> no phase lockstep (the 79-93us disease).
// sign bit = signbit(x) (bit=1 -> -1); halo words = 0 = all +1; pad
// contribution folded into bcorr[class][o] = -Sum_inv(64-2*popc(w_tap)).

#define NN 32
#define CC 64
#define HH 112
#define WW 112
#define OO 64
#define HW (HH*WW)        // 12544
#define G4 (HW/4)         // 3136 quads per channel plane

#define PW 116            // padded width in u64 words (2 left, 2 right)
#define PH 114            // padded height (1 top, 1 bottom)
#define PHW (PW*PH)       // 13224 words per image
#define HALO_PER_IMG 680
#define HALO_TOTAL (NN*HALO_PER_IMG)   // 21760

#define BLK 256
#define PACK_BLOCKS (NN*G4/64)         // 1568

#define CONV_BLK 256
#define CONV_GRID (NN*HH*2/4)          // 1792 blocks; wave = (n,h,ogpair)

typedef int   i32x4 __attribute__((ext_vector_type(4)));
typedef float f4v   __attribute__((ext_vector_type(4)));

// workspace (u64 words): [0,576) wp | [1024,1168) bcorr f32[9][64]
//                        [2048,6656) bft (36 frags x 64 lanes x 16B = 36864B)
//                        [8192, ...) ap (32*13224 words ~3.39MB)

__global__ __launch_bounds__(BLK)
void pack_kernel(const float* __restrict__ act, const float* __restrict__ wgt,
                 uint64_t* __restrict__ ap, uint64_t* __restrict__ wp,
                 float* __restrict__ bcorr, uint32_t* __restrict__ bft) {
    const int b = blockIdx.x;
    const int tid = threadIdx.x;

    if (b == PACK_BLOCKS) {
        // ---- pack weight bit-words (for popcount corrections) ----
        __shared__ uint64_t wl[OO * 9];
        for (int t = tid; t < OO * 9; t += BLK) {
            const int o = t / 9, k = t - o * 9;
            uint32_t lo = 0, hi = 0;
            #pragma unroll
            for (int i = 0; i < 64; ++i) {
                const uint32_t s = __float_as_uint(wgt[(o * 64 + i) * 9 + k]) >> 31;
                if (i < 32) lo |= s << i;
                else        hi |= s << (i - 32);
            }
            const uint64_t w = ((uint64_t)hi << 32) | lo;
            wl[t] = w;
            wp[t] = w;
        }
        __syncthreads();
        // ---- bcorr[class][o] = -Sum_{k invalid in class}(64 - 2*popc(w_ok)) ----
        if (tid < OO) {
            const int o = tid;
            int contrib[9];
            #pragma unroll
            for (int k = 0; k < 9; ++k)
                contrib[k] = 64 - 2 * (int)__popcll(wl[o * 9 + k]);
            #pragma unroll
            for (int ht = 0; ht < 3; ++ht) {
                #pragma unroll
                for (int wt = 0; wt < 3; ++wt) {
                    int sum = 0;
                    #pragma unroll
                    for (int k = 0; k < 9; ++k) {
                        const int kh = k / 3, kw = k - kh * 3;
                        const bool inv = (ht == 0 && kh == 0) || (ht == 2 && kh == 2) ||
                                         (wt == 0 && kw == 0) || (wt == 2 && kw == 2);
                        if (inv) sum += contrib[k];
                    }
                    bcorr[(ht * 3 + wt) * OO + o] = (float)(-sum);
                }
            }
        }
        // ---- B-fragments: frag(tap,og), lane l holds i8 signs of
        //      W[og*16+(l&15)][16*(l>>4)+j], j=0..15 (MFMA B k-order) ----
        for (int idx = tid; idx < 36 * 64; idx += BLK) {
            const int fragid = idx >> 6;         // tap*4 + og
            const int l = idx & 63;
            const int og = fragid & 3, tap = fragid >> 2;
            const int o = og * 16 + (l & 15);
            const int cb = (l >> 4) * 16;
            uint32_t wr[4];
            #pragma unroll
            for (int r = 0; r < 4; ++r) {
                uint32_t v = 0;
                #pragma unroll
                for (int j = 0; j < 4; ++j) {
                    const uint32_t s =
                        __float_as_uint(wgt[(o * 64 + cb + r * 4 + j) * 9 + tap]) >> 31;
                    v |= (s ? 0xFFu : 0x01u) << (8 * j);   // i8 +1 / -1
                }
                wr[r] = v;
            }
            uint32_t* d = bft + (size_t)(fragid * 64 + l) * 4;
            d[0] = wr[0]; d[1] = wr[1]; d[2] = wr[2]; d[3] = wr[3];
        }
        return;
    }

    // ---- distributed halo zeroing: 14 words per block ----
    if (tid < 14) {
        const int i = b * 14 + tid;
        if (i < HALO_TOTAL) {
            const int n = i / HALO_PER_IMG;
            const int j2 = i - n * HALO_PER_IMG;
            int row, col;
            if (j2 < PW)            { row = 0;      col = j2; }
            else if (j2 < 2 * PW)   { row = PH - 1; col = j2 - PW; }
            else {
                const int j3 = j2 - 2 * PW;
                row = 1 + (j3 >> 2);
                const int s = j3 & 3;
                col = (s < 2) ? s : 112 + s;     // cols 0,1,114,115
            }
            ap[(size_t)n * PHW + (size_t)row * PW + col] = 0ull;
        }
    }

    // ---- pack activations (R4-verified): channel-split x4, LDS transpose ----
    __shared__ uint32_t sm[4][4][64];            // [px][q][p]
    const int q = tid >> 6;
    const int p = tid & 63;
    const int G = b * 64 + p;                    // global 4px-group id
    const int n = G / G4;
    const int g = G - n * G4;
    const int h = g / (WW / 4);
    const int w4 = g - h * (WW / 4);

    const uint4* bp = (const uint4*)act + ((size_t)n * CC + q * 16) * G4 + g;
    uint32_t w0a = 0, w1a = 0, w2a = 0, w3a = 0;
    #pragma unroll
    for (int j = 0; j < 16; ++j) {
        const uint4 v = bp[(size_t)j * G4];      // independent 16B loads
        w0a |= (v.x >> 31) << j;
        w1a |= (v.y >> 31) << j;
        w2a |= (v.z >> 31) << j;
        w3a |= (v.w >> 31) << j;
    }
    sm[0][q][p] = w0a;
    sm[1][q][p] = w1a;
    sm[2][q][p] = w2a;
    sm[3][q][p] = w3a;
    __syncthreads();

    if (tid < 64) {                              // wave 0 assembles + stores
        uint64_t A[4];
        #pragma unroll
        for (int j = 0; j < 4; ++j) {
            const uint32_t lo = sm[j][0][p] | (sm[j][1][p] << 16);
            const uint32_t hi = sm[j][2][p] | (sm[j][3][p] << 16);
            A[j] = ((uint64_t)hi << 32) | lo;
        }
        uint64_t* dst = ap + (size_t)n * PHW + (size_t)(h + 1) * PW + (w4 * 4 + 2);
        ulonglong2 v0, v1;
        v0.x = A[0]; v0.y = A[1];
        v1.x = A[2]; v1.y = A[3];
        ((ulonglong2*)dst)[0] = v0;
        ((ulonglong2*)dst)[1] = v1;
    }
}

__global__ __launch_bounds__(CONV_BLK)
void conv_kernel(const uint64_t* __restrict__ ap, const uint32_t* __restrict__ bft,
                 const float* __restrict__ bcorr, float* __restrict__ out) {
    const int gw = (blockIdx.x * CONV_BLK + threadIdx.x) >> 6;  // global wave id
    const int l = threadIdx.x & 63;
    const int pp = gw & 1;                       // og-pair: o in [32pp, 32pp+32)
    const int rh = gw >> 1;                      // 0..3583
    const int n = rh / HH;
    const int h = rh - n * HH;

    const int r16 = l & 15;                      // A row / B col / D col
    const int g   = l >> 4;                      // k-chunk (16 channels)
    const int og0 = 2 * pp;

    // ---- resident B fragments: 9 taps x 2 og ----
    i32x4 bf[9][2];
    #pragma unroll
    for (int t = 0; t < 9; ++t) {
        #pragma unroll
        for (int e = 0; e < 2; ++e) {
            const uint32_t* s = bft + (size_t)(((t * 4) + og0 + e) * 64 + l) * 4;
            bf[t][e] = (i32x4){(int)s[0], (int)s[1], (int)s[2], (int)s[3]};
        }
    }

    // ---- boundary corrections for this (ht, o-lane) ----
    const int ht = (h == 0) ? 0 : ((h == HH - 1) ? 2 : 1);
    float bc[2][3];
    #pragma unroll
    for (int e = 0; e < 2; ++e)
        #pragma unroll
        for (int wt = 0; wt < 3; ++wt)
            bc[e][wt] = bcorr[(ht * 3 + wt) * OO + (og0 + e) * 16 + r16];

    // row pointers (u32 view): tap kh reads packed row h+kh
    const uint32_t* rowp[3];
    #pragma unroll
    for (int kh = 0; kh < 3; ++kh)
        rowp[kh] = (const uint32_t*)(ap + (size_t)n * PHW + (size_t)(h + kh) * PW);

    const int wordsel = g >> 1;                  // which u32 of the u64
    const int shift16 = (g & 1) * 16;

    #pragma unroll 1
    for (int mt = 0; mt < 7; ++mt) {
        const int colbase = 1 + 16 * mt + r16;   // packed col for kw=0
        i32x4 acc0 = {0, 0, 0, 0}, acc1 = {0, 0, 0, 0};
        #pragma unroll
        for (int kh = 0; kh < 3; ++kh) {
            #pragma unroll
            for (int kw = 0; kw < 3; ++kw) {
                const uint32_t raw = rowp[kh][(colbase + kw) * 2 + wordsel];
                const uint32_t c16 = (raw >> shift16) & 0xFFFFu;
                // 16 bits -> 16 i8 (+1/-1): magic-multiply nibble expand
                const uint32_t n0 = c16 & 0xF, n1 = (c16 >> 4) & 0xF;
                const uint32_t n2 = (c16 >> 8) & 0xF, n3 = (c16 >> 12) & 0xF;
                const uint32_t t0 = (n0 * 0x00204081u) & 0x01010101u;
                const uint32_t t1 = (n1 * 0x00204081u) & 0x01010101u;
                const uint32_t t2 = (n2 * 0x00204081u) & 0x01010101u;
                const uint32_t t3 = (n3 * 0x00204081u) & 0x01010101u;
                const i32x4 a = {(int)(0x01010101u ^ (t0 * 0xFEu)),
                                 (int)(0x01010101u ^ (t1 * 0xFEu)),
                                 (int)(0x01010101u ^ (t2 * 0xFEu)),
                                 (int)(0x01010101u ^ (t3 * 0xFEu))};
                const int t9 = kh * 3 + kw;
                acc0 = __builtin_amdgcn_mfma_i32_16x16x64_i8(a, bf[t9][0], acc0, 0, 0, 0);
                acc1 = __builtin_amdgcn_mfma_i32_16x16x64_i8(a, bf[t9][1], acc1, 0, 0, 0);
            }
        }
        // ---- epilogue: D[row=4g+r][col=r16]; w = 16mt + 4g + r ----
        f4v v0, v1;
        #pragma unroll
        for (int r = 0; r < 4; ++r) {
            const int w = 16 * mt + 4 * g + r;
            float c0 = bc[0][1], c1 = bc[1][1];
            if (w == 0)      { c0 = bc[0][0]; c1 = bc[1][0]; }
            if (w == WW - 1) { c0 = bc[0][2]; c1 = bc[1][2]; }
            v0[r] = (float)acc0[r] + c0;
            v1[r] = (float)acc1[r] + c1;
        }
        float* op = out + ((size_t)n * OO + og0 * 16 + r16) * HW
                  + (size_t)h * WW + 16 * mt + 4 * g;
        __builtin_nontemporal_store(v0, (f4v*)op);
        __builtin_nontemporal_store(v1, (f4v*)(op + (size_t)16 * HW));
    }
}

extern "C" void kernel_launch(void* const* d_in, const int* in_sizes, int n_in,
                              void* d_out, int out_size, void* d_ws, size_t ws_size,
                              hipStream_t stream) {
    const float* act = (const float*)d_in[0];
    const float* wgt = (const float*)d_in[1];
    float* out = (float*)d_out;

    uint64_t* wp = (uint64_t*)d_ws;              // [0,576)
    float* bcorr = (float*)(wp + 1024);          // 288 f32
    uint32_t* bft = (uint32_t*)(wp + 2048);      // 36864 B
    uint64_t* ap = wp + 8192;                    // 32*13224 words

    pack_kernel<<<PACK_BLOCKS + 1, BLK, 0, stream>>>(act, wgt, ap, wp, bcorr, bft);
    conv_kernel<<<CONV_GRID, CONV_BLK, 0, stream>>>(ap, bft, bcorr, out);
}